// Round 1
// baseline (535.993 us; speedup 1.0000x reference)
//
#include <hip/hip_runtime.h>
#include <math.h>

// Problem constants (B=1)
#define TT   192      // sequence length T
#define HH   1024     // hidden H
#define NHH  16       // heads
#define HD   64       // head dim
#define H3   3072     // 3*H
#define LN_EPS 1e-5f

// -------------------------------------------------------------------------
// NOTE ON CORRECTNESS: the reference's entire build_edges branch is
// numerically dead: edges = softmax(scores, -1) is only consumed as
// edges.sum(-1) == 1.0, so ew == 1/(T+1e-6) is a constant added uniformly
// along the attention softmax axis -> no effect on the output (softmax
// shift invariance). Output == 2 layers of plain MHA + LN + residual.
// -------------------------------------------------------------------------

// C[M,N] = A[M,K] @ B[N,K]^T + bias[N]   (A,B row-major; M%64==0,N%64==0,K%16==0)
__global__ __launch_bounds__(256) void gemm_bt(const float* __restrict__ A,
                                               const float* __restrict__ Bw,
                                               const float* __restrict__ bias,
                                               float* __restrict__ C,
                                               int M, int N, int K)
{
    __shared__ float As[16][65];
    __shared__ float Bs[16][65];
    const int tid = threadIdx.x;
    const int m0 = blockIdx.y * 64;
    const int n0 = blockIdx.x * 64;
    const int lr = tid >> 2;          // 0..63: row within tile
    const int lk = (tid & 3) << 2;    // 0,4,8,12: k within tile
    const int ty = tid >> 4;          // 0..15
    const int tx = tid & 15;          // 0..15

    float acc[4][4] = {};

    for (int k0 = 0; k0 < K; k0 += 16) {
        float4 av = *(const float4*)&A [(m0 + lr) * K + k0 + lk];
        float4 bv = *(const float4*)&Bw[(n0 + lr) * K + k0 + lk];
        __syncthreads();   // previous iteration's LDS reads complete
        As[lk + 0][lr] = av.x; As[lk + 1][lr] = av.y;
        As[lk + 2][lr] = av.z; As[lk + 3][lr] = av.w;
        Bs[lk + 0][lr] = bv.x; Bs[lk + 1][lr] = bv.y;
        Bs[lk + 2][lr] = bv.z; Bs[lk + 3][lr] = bv.w;
        __syncthreads();
        #pragma unroll
        for (int kk = 0; kk < 16; ++kk) {
            float a[4], b[4];
            #pragma unroll
            for (int i = 0; i < 4; ++i) a[i] = As[kk][ty + 16 * i];
            #pragma unroll
            for (int j = 0; j < 4; ++j) b[j] = Bs[kk][tx + 16 * j];
            #pragma unroll
            for (int i = 0; i < 4; ++i)
                #pragma unroll
                for (int j = 0; j < 4; ++j)
                    acc[i][j] = fmaf(a[i], b[j], acc[i][j]);
        }
    }

    #pragma unroll
    for (int i = 0; i < 4; ++i) {
        const int m = m0 + ty + 16 * i;
        #pragma unroll
        for (int j = 0; j < 4; ++j) {
            const int n = n0 + tx + 16 * j;
            C[m * N + n] = acc[i][j] + bias[n];
        }
    }
}

// One block per (head, query row). qkv: [T, 3H] with q|k|v chunks.
// O[q, h*64+d] = sum_k softmax_k(q.k/8) * v[k,d]
__global__ __launch_bounds__(192) void attn_kernel(const float* __restrict__ qkv,
                                                   float* __restrict__ O)
{
    const int h = blockIdx.x;
    const int q = blockIdx.y;
    const int t = threadIdx.x;      // 0..191 == key index

    __shared__ float qv[HD];
    __shared__ float p[TT];

    if (t < HD) qv[t] = qkv[q * H3 + h * HD + t];
    __syncthreads();

    const float* Krow = &qkv[t * H3 + HH + h * HD];
    float s = 0.f;
    #pragma unroll 8
    for (int d = 0; d < HD; ++d) s = fmaf(qv[d], Krow[d], s);
    s *= 0.125f;                    // 1/sqrt(hd)

    p[t] = s;
    __syncthreads();
    float mx = -1e30f;
    for (int k = 0; k < TT; ++k) mx = fmaxf(mx, p[k]);   // LDS broadcast reads
    const float e = __expf(s - mx);
    __syncthreads();
    p[t] = e;
    __syncthreads();
    float sum = 0.f;
    for (int k = 0; k < TT; ++k) sum += p[k];
    const float inv = 1.f / sum;

    if (t < HD) {
        const int d = t;
        float acc = 0.f;
        for (int k = 0; k < TT; ++k)
            acc = fmaf(p[k], qkv[k * H3 + 2 * HH + h * HD + d], acc);
        O[q * HH + h * HD + d] = acc * inv;
    }
}

// xout[row,:] = xin[row,:] + LN(y[row,:]) * g + b      (one block per row)
__global__ __launch_bounds__(256) void ln_residual(const float* __restrict__ y,
                                                   const float* __restrict__ xin,
                                                   const float* __restrict__ g,
                                                   const float* __restrict__ b,
                                                   float* __restrict__ xout)
{
    const int row = blockIdx.x;
    const int tid = threadIdx.x;    // 256 threads, 4 elems each

    const float4 v = *(const float4*)&y[row * HH + tid * 4];
    float s  = v.x + v.y + v.z + v.w;
    float sq = v.x * v.x + v.y * v.y + v.z * v.z + v.w * v.w;

    #pragma unroll
    for (int off = 32; off > 0; off >>= 1) {
        s  += __shfl_down(s,  off);
        sq += __shfl_down(sq, off);
    }
    __shared__ float ws[4], wq[4];
    const int wave = tid >> 6;
    if ((tid & 63) == 0) { ws[wave] = s; wq[wave] = sq; }
    __syncthreads();
    float ts = 0.f, tq = 0.f;
    #pragma unroll
    for (int w = 0; w < 4; ++w) { ts += ws[w]; tq += wq[w]; }

    const float mean = ts * (1.f / HH);
    const float var  = tq * (1.f / HH) - mean * mean;
    const float r    = rsqrtf(var + LN_EPS);

    const float4 xi = *(const float4*)&xin[row * HH + tid * 4];
    const float4 gg = *(const float4*)&g[tid * 4];
    const float4 bb = *(const float4*)&b[tid * 4];
    float4 o;
    o.x = xi.x + (v.x - mean) * r * gg.x + bb.x;
    o.y = xi.y + (v.y - mean) * r * gg.y + bb.y;
    o.z = xi.z + (v.z - mean) * r * gg.z + bb.z;
    o.w = xi.w + (v.w - mean) * r * gg.w + bb.w;
    *(float4*)&xout[row * HH + tid * 4] = o;
}

extern "C" void kernel_launch(void* const* d_in, const int* in_sizes, int n_in,
                              void* d_out, int out_size, void* d_ws, size_t ws_size,
                              hipStream_t stream)
{
    const float* nodes     = (const float*)d_in[0];
    const float* mha_in_w  = (const float*)d_in[14];   // [2, 3H, H]
    const float* mha_in_b  = (const float*)d_in[15];   // [2, 3H]
    const float* mha_out_w = (const float*)d_in[16];   // [2, H, H]
    const float* mha_out_b = (const float*)d_in[17];   // [2, H]
    const float* mha_ln_g  = (const float*)d_in[18];   // [2, H]
    const float* mha_ln_b  = (const float*)d_in[19];   // [2, H]
    float* out = (float*)d_out;

    float* ws     = (float*)d_ws;
    float* qkv    = ws;                  // T*3H
    float* attn_o = qkv + TT * H3;       // T*H
    float* proj   = attn_o + TT * HH;    // T*H
    float* x1     = proj + TT * HH;      // T*H

    const float* x = nodes;
    for (int l = 0; l < 2; ++l) {
        float* xout = (l == 0) ? x1 : out;

        gemm_bt<<<dim3(H3 / 64, TT / 64), 256, 0, stream>>>(
            x, mha_in_w + (size_t)l * H3 * HH, mha_in_b + l * H3, qkv, TT, H3, HH);

        attn_kernel<<<dim3(NHH, TT), 192, 0, stream>>>(qkv, attn_o);

        gemm_bt<<<dim3(HH / 64, TT / 64), 256, 0, stream>>>(
            attn_o, mha_out_w + (size_t)l * HH * HH, mha_out_b + l * HH, proj, TT, HH, HH);

        ln_residual<<<TT, 256, 0, stream>>>(
            proj, x, mha_ln_g + l * HH, mha_ln_b + l * HH, xout);

        x = xout;
    }
}

// Round 2
// 260.166 us; speedup vs baseline: 2.0602x; 2.0602x over previous
//
#include <hip/hip_runtime.h>
#include <math.h>

// Problem constants (B=1)
#define TT   192      // sequence length T
#define HH   1024     // hidden H
#define NHH  16       // heads
#define HD   64       // head dim
#define H3   3072     // 3*H
#define LN_EPS 1e-5f

// -------------------------------------------------------------------------
// build_edges is numerically dead: edges=softmax(scores,-1) is consumed only
// as edges.sum(-1)==1.0 -> ew is constant along the attention softmax axis ->
// softmax shift invariance -> output == 2 layers of plain MHA + LN + residual.
// -------------------------------------------------------------------------

typedef __attribute__((ext_vector_type(4))) float floatx4;
typedef __attribute__((ext_vector_type(8))) short short8;

static __device__ inline short f2bf(float f) {
    union { float f; unsigned u; } v; v.f = f;
    unsigned r = (v.u + 0x7fffu + ((v.u >> 16) & 1u)) >> 16;  // RNE
    return (short)r;
}

#define LDA 40   // padded LDS row stride in shorts (80 B: 16B-aligned, 2-way banks = free)

// C[M,N] = A[M,K] @ B[N,K]^T + bias[N], bf16 MFMA with on-the-fly fp32->bf16.
// M%64==0, N%64==0, K%32==0. Block 256 = 4 waves; 64x64 tile; BK=32.
__global__ __launch_bounds__(256) void gemm_bt_mfma(const float* __restrict__ A,
                                                    const float* __restrict__ Bw,
                                                    const float* __restrict__ bias,
                                                    float* __restrict__ C,
                                                    int M, int N, int K)
{
    __shared__ short As[64 * LDA];
    __shared__ short Bs[64 * LDA];
    const int tid  = threadIdx.x;
    const int wave = tid >> 6;
    const int lane = tid & 63;
    const int quad = lane >> 4;
    const int l16  = lane & 15;
    const int m0 = blockIdx.y * 64;
    const int n0 = blockIdx.x * 64;

    // staging: thread loads 8 consecutive floats of one row
    const int trow = tid >> 2;          // 0..63
    const int tcol = (tid & 3) << 3;    // 0,8,16,24

    const float* Ag = A  + (size_t)(m0 + trow) * K + tcol;
    const float* Bg = Bw + (size_t)(n0 + trow) * K + tcol;

    floatx4 acc[4] = {};

    float4 a0 = *(const float4*)(Ag);
    float4 a1 = *(const float4*)(Ag + 4);
    float4 b0 = *(const float4*)(Bg);
    float4 b1 = *(const float4*)(Bg + 4);

    for (int k0 = 0; k0 < K; k0 += 32) {
        __syncthreads();   // previous iteration's LDS reads done
        short8 av, bv;
        av[0] = f2bf(a0.x); av[1] = f2bf(a0.y); av[2] = f2bf(a0.z); av[3] = f2bf(a0.w);
        av[4] = f2bf(a1.x); av[5] = f2bf(a1.y); av[6] = f2bf(a1.z); av[7] = f2bf(a1.w);
        bv[0] = f2bf(b0.x); bv[1] = f2bf(b0.y); bv[2] = f2bf(b0.z); bv[3] = f2bf(b0.w);
        bv[4] = f2bf(b1.x); bv[5] = f2bf(b1.y); bv[6] = f2bf(b1.z); bv[7] = f2bf(b1.w);
        *(short8*)&As[trow * LDA + tcol] = av;
        *(short8*)&Bs[trow * LDA + tcol] = bv;
        __syncthreads();

        if (k0 + 32 < K) {   // register prefetch of next tile; hidden by MFMA
            a0 = *(const float4*)(Ag + k0 + 32);
            a1 = *(const float4*)(Ag + k0 + 36);
            b0 = *(const float4*)(Bg + k0 + 32);
            b1 = *(const float4*)(Bg + k0 + 36);
        }

        // A-frag: A[m=lane&15][k=quad*8+j]; wave owns m-rows [wave*16, wave*16+16)
        short8 af = *(short8*)&As[(wave * 16 + l16) * LDA + quad * 8];
        #pragma unroll
        for (int nt = 0; nt < 4; ++nt) {
            short8 bf = *(short8*)&Bs[(nt * 16 + l16) * LDA + quad * 8];
            acc[nt] = __builtin_amdgcn_mfma_f32_16x16x32_bf16(af, bf, acc[nt], 0, 0, 0);
        }
    }

    // C/D layout: col = lane&15, row = quad*4 + reg
    #pragma unroll
    for (int nt = 0; nt < 4; ++nt) {
        const int col = n0 + nt * 16 + l16;
        const float bz = bias[col];
        #pragma unroll
        for (int r = 0; r < 4; ++r) {
            const int row = m0 + wave * 16 + quad * 4 + r;
            C[(size_t)row * N + col] = acc[nt][r] + bz;
        }
    }
}

// One block (192 thr = 3 waves) per (head, query). Shuffle softmax, split PV.
__global__ __launch_bounds__(192) void attn_kernel(const float* __restrict__ qkv,
                                                   float* __restrict__ O)
{
    const int h = blockIdx.x;
    const int q = blockIdx.y;
    const int t = threadIdx.x;
    const int wave = t >> 6, lane = t & 63;

    __shared__ float qv[HD];
    __shared__ float p[TT];
    __shared__ float red[3], red2[3];
    __shared__ float ov[3][HD];

    if (t < HD) qv[t] = qkv[q * H3 + h * HD + t];
    __syncthreads();

    // scores: thread t = key t; float4 K loads (L2-resident)
    const float4* K4 = (const float4*)(qkv + (size_t)t * H3 + HH + h * HD);
    const float4* q4 = (const float4*)qv;
    float s = 0.f;
    #pragma unroll
    for (int i = 0; i < 16; ++i) {
        float4 kv = K4[i];
        float4 qq = q4[i];
        s += kv.x * qq.x + kv.y * qq.y + kv.z * qq.z + kv.w * qq.w;
    }
    s *= 0.125f;   // 1/sqrt(64)

    // max via wave shuffles + 3-way LDS combine
    float m = s;
    #pragma unroll
    for (int off = 32; off; off >>= 1) m = fmaxf(m, __shfl_xor(m, off));
    if (lane == 0) red[wave] = m;
    __syncthreads();
    m = fmaxf(fmaxf(red[0], red[1]), red[2]);

    const float e = __expf(s - m);
    p[t] = e;
    float sm = e;
    #pragma unroll
    for (int off = 32; off; off >>= 1) sm += __shfl_xor(sm, off);
    if (lane == 0) red2[wave] = sm;
    __syncthreads();
    const float inv = 1.f / (red2[0] + red2[1] + red2[2]);

    // PV: wave w covers keys [w*64, w*64+64), lane = d (coalesced V loads)
    const float* Vb = qkv + 2 * HH + h * HD + lane;
    float acc = 0.f;
    #pragma unroll 8
    for (int kk = 0; kk < 64; ++kk) {
        const int k = wave * 64 + kk;
        acc = fmaf(p[k], Vb[(size_t)k * H3], acc);
    }
    ov[wave][lane] = acc;
    __syncthreads();
    if (t < HD)
        O[q * HH + h * HD + t] = (ov[0][t] + ov[1][t] + ov[2][t]) * inv;
}

// xout[row,:] = xin[row,:] + LN(y[row,:]) * g + b      (one block per row)
__global__ __launch_bounds__(256) void ln_residual(const float* __restrict__ y,
                                                   const float* __restrict__ xin,
                                                   const float* __restrict__ g,
                                                   const float* __restrict__ b,
                                                   float* __restrict__ xout)
{
    const int row = blockIdx.x;
    const int tid = threadIdx.x;

    const float4 v = *(const float4*)&y[row * HH + tid * 4];
    float s  = v.x + v.y + v.z + v.w;
    float sq = v.x * v.x + v.y * v.y + v.z * v.z + v.w * v.w;

    #pragma unroll
    for (int off = 32; off > 0; off >>= 1) {
        s  += __shfl_down(s,  off);
        sq += __shfl_down(sq, off);
    }
    __shared__ float ws[4], wq[4];
    const int wave = tid >> 6;
    if ((tid & 63) == 0) { ws[wave] = s; wq[wave] = sq; }
    __syncthreads();
    float ts = 0.f, tq = 0.f;
    #pragma unroll
    for (int w = 0; w < 4; ++w) { ts += ws[w]; tq += wq[w]; }

    const float mean = ts * (1.f / HH);
    const float var  = tq * (1.f / HH) - mean * mean;
    const float r    = rsqrtf(var + LN_EPS);

    const float4 xi = *(const float4*)&xin[row * HH + tid * 4];
    const float4 gg = *(const float4*)&g[tid * 4];
    const float4 bb = *(const float4*)&b[tid * 4];
    float4 o;
    o.x = xi.x + (v.x - mean) * r * gg.x + bb.x;
    o.y = xi.y + (v.y - mean) * r * gg.y + bb.y;
    o.z = xi.z + (v.z - mean) * r * gg.z + bb.z;
    o.w = xi.w + (v.w - mean) * r * gg.w + bb.w;
    *(float4*)&xout[row * HH + tid * 4] = o;
}

extern "C" void kernel_launch(void* const* d_in, const int* in_sizes, int n_in,
                              void* d_out, int out_size, void* d_ws, size_t ws_size,
                              hipStream_t stream)
{
    const float* nodes     = (const float*)d_in[0];
    const float* mha_in_w  = (const float*)d_in[14];   // [2, 3H, H]
    const float* mha_in_b  = (const float*)d_in[15];   // [2, 3H]
    const float* mha_out_w = (const float*)d_in[16];   // [2, H, H]
    const float* mha_out_b = (const float*)d_in[17];   // [2, H]
    const float* mha_ln_g  = (const float*)d_in[18];   // [2, H]
    const float* mha_ln_b  = (const float*)d_in[19];   // [2, H]
    float* out = (float*)d_out;

    float* ws     = (float*)d_ws;
    float* qkv    = ws;                  // T*3H
    float* attn_o = qkv + TT * H3;       // T*H
    float* proj   = attn_o + TT * HH;    // T*H
    float* x1     = proj + TT * HH;      // T*H

    const float* x = nodes;
    for (int l = 0; l < 2; ++l) {
        float* xout = (l == 0) ? x1 : out;

        gemm_bt_mfma<<<dim3(H3 / 64, TT / 64), 256, 0, stream>>>(
            x, mha_in_w + (size_t)l * H3 * HH, mha_in_b + l * H3, qkv, TT, H3, HH);

        attn_kernel<<<dim3(NHH, TT), 192, 0, stream>>>(qkv, attn_o);

        gemm_bt_mfma<<<dim3(HH / 64, TT / 64), 256, 0, stream>>>(
            attn_o, mha_out_w + (size_t)l * HH * HH, mha_out_b + l * HH, proj, TT, HH, HH);

        ln_residual<<<TT, 256, 0, stream>>>(
            proj, x, mha_ln_g + l * HH, mha_ln_b + l * HH, xout);

        x = xout;
    }
}

// Round 3
// 212.580 us; speedup vs baseline: 2.5214x; 1.2239x over previous
//
#include <hip/hip_runtime.h>
#include <math.h>

// Problem constants (B=1)
#define TT   192      // sequence length T
#define HH   1024     // hidden H
#define NHH  16       // heads
#define HD   64       // head dim
#define H3   3072     // 3*H
#define LN_EPS 1e-5f

// -------------------------------------------------------------------------
// build_edges is numerically dead: edges=softmax(scores,-1) is consumed only
// as edges.sum(-1)==1.0 -> ew constant along attention softmax axis ->
// softmax shift invariance -> output == 2 layers of plain MHA + LN + residual.
// -------------------------------------------------------------------------

typedef __attribute__((ext_vector_type(4))) float floatx4;
typedef __attribute__((ext_vector_type(8))) short short8;

static __device__ inline unsigned short f2bf(float f) {
    union { float f; unsigned u; } v; v.f = f;
    return (unsigned short)((v.u + 0x7fffu + ((v.u >> 16) & 1u)) >> 16);  // RNE
}
static __device__ inline float bf2f(unsigned short s) {
    union { unsigned u; float f; } v; v.u = ((unsigned)s) << 16;
    return v.f;
}

// grid-stride fp32 -> bf16 (n % 4 == 0)
__global__ __launch_bounds__(256) void cvt_bf16(const float* __restrict__ src,
                                                unsigned short* __restrict__ dst,
                                                int n4)
{
    int i = blockIdx.x * 256 + threadIdx.x;
    if (i >= n4) return;
    float4 v = ((const float4*)src)[i];
    ushort4 o;
    o.x = f2bf(v.x); o.y = f2bf(v.y); o.z = f2bf(v.z); o.w = f2bf(v.w);
    ((ushort4*)dst)[i] = o;
}

__device__ inline void store_c(float* C, size_t i, float v)          { C[i] = v; }
__device__ inline void store_c(unsigned short* C, size_t i, float v) { C[i] = f2bf(v); }

#define GLD(gp, lp) __builtin_amdgcn_global_load_lds( \
    (const __attribute__((address_space(1))) void*)(gp), \
    (__attribute__((address_space(3))) void*)(lp), 16, 0, 0)

// C[M,N] = A[M,K] @ B[N,K]^T + bias[N].  A,B bf16 row-major; C fp32 or bf16.
// M%64==0, N%64==0, K%64==0. Block = 256 thr = 4 waves; tile 64x64, BK=64.
// Staging: global_load_lds dwordx4, XOR-swizzled chunks (slot = chunk ^ (row&7))
// so unpadded LDS fragment reads are bank-conflict-free.
template <typename OutT>
__global__ __launch_bounds__(256) void gemm_bf16(const unsigned short* __restrict__ A,
                                                 const unsigned short* __restrict__ Bw,
                                                 const float* __restrict__ bias,
                                                 OutT* __restrict__ C,
                                                 int M, int N, int K)
{
    __shared__ unsigned short As[64 * 64];
    __shared__ unsigned short Bs[64 * 64];
    const int tid  = threadIdx.x;
    const int w    = tid >> 6;
    const int lane = tid & 63;
    const int quad = lane >> 4;
    const int l16  = lane & 15;
    const int m0 = blockIdx.y * 64;
    const int n0 = blockIdx.x * 64;

    // Per-lane global source for async staging. Lane l covers tile row
    // (base + l>>3), 16-B chunk slot (l&7). Source chunk = (l&7) ^ (l>>3)
    // implements the XOR swizzle (slot = g ^ (row&7)).
    const int lrow   = lane >> 3;              // 0..7
    const int lchunk = (lane & 7) ^ lrow;      // swizzled source chunk
    const unsigned short* Ag = A  + (size_t)(m0 + w * 16 + lrow) * K + lchunk * 8;
    const unsigned short* Bg = Bw + (size_t)(n0 + w * 16 + lrow) * K + lchunk * 8;

    floatx4 acc[4] = {};

    const int niter = K >> 6;
    for (int it = 0; it < niter; ++it) {
        const int k0 = it << 6;
        __syncthreads();                     // prev iteration's LDS reads done
        // wave w stages A rows [w*16, w*16+16) and B rows [w*16, w*16+16)
        GLD(Ag + k0,         As + (w * 16    ) * 64);
        GLD(Ag + 8 * K + k0, As + (w * 16 + 8) * 64);
        GLD(Bg + k0,         Bs + (w * 16    ) * 64);
        GLD(Bg + 8 * K + k0, Bs + (w * 16 + 8) * 64);
        __syncthreads();                     // vmcnt(0) drain: tile resident

        #pragma unroll
        for (int s = 0; s < 2; ++s) {
            const int slot = (s * 4 + quad) ^ (l16 & 7);
            short8 af = *(const short8*)&As[(w * 16 + l16) * 64 + slot * 8];
            #pragma unroll
            for (int nt = 0; nt < 4; ++nt) {
                short8 bf = *(const short8*)&Bs[(nt * 16 + l16) * 64 + slot * 8];
                acc[nt] = __builtin_amdgcn_mfma_f32_16x16x32_bf16(af, bf, acc[nt], 0, 0, 0);
            }
        }
    }

    // C/D layout: col = lane&15, row = quad*4 + reg
    #pragma unroll
    for (int nt = 0; nt < 4; ++nt) {
        const int col = n0 + nt * 16 + l16;
        const float bz = bias[col];
        #pragma unroll
        for (int r = 0; r < 4; ++r) {
            const int row = m0 + w * 16 + quad * 4 + r;
            store_c(C, (size_t)row * N + col, acc[nt][r] + bz);
        }
    }
}

// One block (192 thr = 3 waves) per (head, query). bf16 qkv in, bf16 O out.
__global__ __launch_bounds__(192) void attn_bf16(const unsigned short* __restrict__ qkv,
                                                 unsigned short* __restrict__ O)
{
    const int h = blockIdx.x;
    const int q = blockIdx.y;
    const int t = threadIdx.x;
    const int wv = t >> 6, lane = t & 63;

    __shared__ float qv[HD];
    __shared__ float p[TT];
    __shared__ float red[3], red2[3];
    __shared__ float ov[3][HD];

    if (t < HD) qv[t] = bf2f(qkv[q * H3 + h * HD + t]);
    __syncthreads();

    // scores: thread t = key t; 16-B bf16 K loads
    const uint4* K4 = (const uint4*)(qkv + (size_t)t * H3 + HH + h * HD);
    float s = 0.f;
    #pragma unroll
    for (int i = 0; i < 8; ++i) {
        uint4 kv = K4[i];
        unsigned uu[4] = {kv.x, kv.y, kv.z, kv.w};
        #pragma unroll
        for (int jj = 0; jj < 4; ++jj) {
            union { unsigned u; float f; } lo, hi;
            lo.u = uu[jj] << 16;
            hi.u = uu[jj] & 0xffff0000u;
            s = fmaf(lo.f, qv[i * 8 + jj * 2 + 0], s);
            s = fmaf(hi.f, qv[i * 8 + jj * 2 + 1], s);
        }
    }
    s *= 0.125f;   // 1/sqrt(64)

    // max via wave shuffles + 3-way LDS combine
    float m = s;
    #pragma unroll
    for (int off = 32; off; off >>= 1) m = fmaxf(m, __shfl_xor(m, off));
    if (lane == 0) red[wv] = m;
    __syncthreads();
    m = fmaxf(fmaxf(red[0], red[1]), red[2]);

    const float e = __expf(s - m);
    p[t] = e;
    float sm = e;
    #pragma unroll
    for (int off = 32; off; off >>= 1) sm += __shfl_xor(sm, off);
    if (lane == 0) red2[wv] = sm;
    __syncthreads();
    const float inv = 1.f / (red2[0] + red2[1] + red2[2]);

    // PV: wave wv covers keys [wv*64, wv*64+64), lane = d (coalesced loads)
    const unsigned short* Vb = qkv + 2 * HH + h * HD + lane;
    float acc = 0.f;
    #pragma unroll 8
    for (int kk = 0; kk < 64; ++kk) {
        const int k = wv * 64 + kk;
        acc = fmaf(p[k], bf2f(Vb[(size_t)k * H3]), acc);
    }
    ov[wv][lane] = acc;
    __syncthreads();
    if (t < HD)
        O[q * HH + h * HD + t] = f2bf((ov[0][t] + ov[1][t] + ov[2][t]) * inv);
}

// xout = xin + LN(y)*g + b ; dual write fp32 + bf16  (one block per row)
__global__ __launch_bounds__(256) void ln_residual(const float* __restrict__ y,
                                                   const float* __restrict__ xin,
                                                   const float* __restrict__ g,
                                                   const float* __restrict__ b,
                                                   float* __restrict__ xout,
                                                   unsigned short* __restrict__ xout_bf)
{
    const int row = blockIdx.x;
    const int tid = threadIdx.x;

    const float4 v = *(const float4*)&y[row * HH + tid * 4];
    float s  = v.x + v.y + v.z + v.w;
    float sq = v.x * v.x + v.y * v.y + v.z * v.z + v.w * v.w;

    #pragma unroll
    for (int off = 32; off > 0; off >>= 1) {
        s  += __shfl_down(s,  off);
        sq += __shfl_down(sq, off);
    }
    __shared__ float ws[4], wq[4];
    const int wave = tid >> 6;
    if ((tid & 63) == 0) { ws[wave] = s; wq[wave] = sq; }
    __syncthreads();
    float ts = 0.f, tq = 0.f;
    #pragma unroll
    for (int w = 0; w < 4; ++w) { ts += ws[w]; tq += wq[w]; }

    const float mean = ts * (1.f / HH);
    const float var  = tq * (1.f / HH) - mean * mean;
    const float r    = rsqrtf(var + LN_EPS);

    const float4 xi = *(const float4*)&xin[row * HH + tid * 4];
    const float4 gg = *(const float4*)&g[tid * 4];
    const float4 bb = *(const float4*)&b[tid * 4];
    float4 o;
    o.x = xi.x + (v.x - mean) * r * gg.x + bb.x;
    o.y = xi.y + (v.y - mean) * r * gg.y + bb.y;
    o.z = xi.z + (v.z - mean) * r * gg.z + bb.z;
    o.w = xi.w + (v.w - mean) * r * gg.w + bb.w;
    *(float4*)&xout[row * HH + tid * 4] = o;
    ushort4 ob;
    ob.x = f2bf(o.x); ob.y = f2bf(o.y); ob.z = f2bf(o.z); ob.w = f2bf(o.w);
    *(ushort4*)&xout_bf[row * HH + tid * 4] = ob;
}

extern "C" void kernel_launch(void* const* d_in, const int* in_sizes, int n_in,
                              void* d_out, int out_size, void* d_ws, size_t ws_size,
                              hipStream_t stream)
{
    const float* nodes     = (const float*)d_in[0];
    const float* mha_in_w  = (const float*)d_in[14];   // [2, 3H, H]
    const float* mha_in_b  = (const float*)d_in[15];   // [2, 3H]
    const float* mha_out_w = (const float*)d_in[16];   // [2, H, H]
    const float* mha_out_b = (const float*)d_in[17];   // [2, H]
    const float* mha_ln_g  = (const float*)d_in[18];   // [2, H]
    const float* mha_ln_b  = (const float*)d_in[19];   // [2, H]
    float* out = (float*)d_out;

    // ---- ws carve (bf16 region then fp32 region) ----
    unsigned short* u = (unsigned short*)d_ws;
    unsigned short* bf_inW   = u;  u += 2 * H3 * HH;    // 6291456
    unsigned short* bf_outW  = u;  u += 2 * HH * HH;    // 2097152
    unsigned short* bf_nodes = u;  u += TT * HH;        // 196608
    unsigned short* bf_x1    = u;  u += TT * HH;
    unsigned short* bf_qkv   = u;  u += TT * H3;
    unsigned short* bf_o     = u;  u += TT * HH;
    float* f = (float*)u;
    float* proj = f;  f += TT * HH;
    float* x1   = f;  f += TT * HH;

    // ---- one-time fp32 -> bf16 conversion (weights + nodes) ----
    {
        int n4 = (2 * H3 * HH) / 4;
        cvt_bf16<<<(n4 + 255) / 256, 256, 0, stream>>>(mha_in_w, bf_inW, n4);
        n4 = (2 * HH * HH) / 4;
        cvt_bf16<<<(n4 + 255) / 256, 256, 0, stream>>>(mha_out_w, bf_outW, n4);
        n4 = (TT * HH) / 4;
        cvt_bf16<<<(n4 + 255) / 256, 256, 0, stream>>>(nodes, bf_nodes, n4);
    }

    const float* x_f = nodes;
    const unsigned short* x_bf = bf_nodes;
    for (int l = 0; l < 2; ++l) {
        float* xout = (l == 0) ? x1 : out;

        gemm_bf16<unsigned short><<<dim3(H3 / 64, TT / 64), 256, 0, stream>>>(
            x_bf, bf_inW + (size_t)l * H3 * HH, mha_in_b + l * H3, bf_qkv, TT, H3, HH);

        attn_bf16<<<dim3(NHH, TT), 192, 0, stream>>>(bf_qkv, bf_o);

        gemm_bf16<float><<<dim3(HH / 64, TT / 64), 256, 0, stream>>>(
            bf_o, bf_outW + (size_t)l * HH * HH, mha_out_b + l * HH, proj, TT, HH, HH);

        ln_residual<<<TT, 256, 0, stream>>>(
            proj, x_f, mha_ln_g + l * HH, mha_ln_b + l * HH, xout, bf_x1);

        x_f = xout;
        x_bf = bf_x1;
    }
}

// Round 4
// 170.084 us; speedup vs baseline: 3.1513x; 1.2498x over previous
//
#include <hip/hip_runtime.h>
#include <math.h>

// Problem constants (B=1)
#define TT   192      // sequence length T
#define HH   1024     // hidden H
#define NHH  16       // heads
#define HD   64       // head dim
#define H3   3072     // 3*H
#define VTS  200      // Vt row stride in shorts (padded: 400 B -> conflict-free LDS)
#define LN_EPS 1e-5f

// -------------------------------------------------------------------------
// build_edges is numerically dead: edges=softmax(scores,-1) is consumed only
// as edges.sum(-1)==1.0 -> ew constant along attention softmax axis ->
// softmax shift invariance -> output == 2 layers of plain MHA + LN + residual.
// -------------------------------------------------------------------------

typedef __attribute__((ext_vector_type(4))) float floatx4;
typedef __attribute__((ext_vector_type(8))) short short8;

static __device__ inline unsigned short f2bf(float f) {
    union { float f; unsigned u; } v; v.f = f;
    return (unsigned short)((v.u + 0x7fffu + ((v.u >> 16) & 1u)) >> 16);  // RNE
}

// fused fp32->bf16 of the three sources in one dispatch
__global__ __launch_bounds__(256) void cvt3(const float* __restrict__ a, int na4,
                                            const float* __restrict__ b, int nb4,
                                            const float* __restrict__ c, int nc4,
                                            unsigned short* __restrict__ da,
                                            unsigned short* __restrict__ db,
                                            unsigned short* __restrict__ dc)
{
    int j = blockIdx.x * 256 + threadIdx.x;
    const float* s; unsigned short* d;
    if (j < na4)                 { s = a; d = da; }
    else if ((j -= na4) < nb4)   { s = b; d = db; }
    else if ((j -= nb4) < nc4)   { s = c; d = dc; }
    else return;
    float4 v = ((const float4*)s)[j];
    ushort4 o;
    o.x = f2bf(v.x); o.y = f2bf(v.y); o.z = f2bf(v.z); o.w = f2bf(v.w);
    ((ushort4*)d)[j] = o;
}

__device__ inline void store_c(float* C, size_t i, float v)          { C[i] = v; }
__device__ inline void store_c(unsigned short* C, size_t i, float v) { C[i] = f2bf(v); }

#define GLD(gp, lp) __builtin_amdgcn_global_load_lds( \
    (const __attribute__((address_space(1))) void*)(gp), \
    (__attribute__((address_space(3))) void*)(lp), 16, 0, 0)

// C[M,N] = A[M,K] @ B[N,K]^T + bias[N].  A,B bf16 row-major.
// Tile 64x64, BK=256 (4 iterations at K=1024): 16 async loads in flight per
// wave per iteration to amortize the vmcnt(0) barrier drain.
// XOR swizzle: LDS(row, slot32) holds source chunk slot32 ^ (row&7), so both
// the lane-contiguous global_load_lds staging and the ds_read_b128 fragment
// reads are bank-conflict-free with an unpadded 512-B row.
// If VT_SPLIT: output cols >= 2H are written TRANSPOSED as bf16 Vt[d][t]
// (stride VTS) for the attention kernel's PV operand; cols < 2H go to C.
template <typename OutT, int VT_SPLIT>
__global__ __launch_bounds__(256) void gemm_bf16(const unsigned short* __restrict__ A,
                                                 const unsigned short* __restrict__ Bw,
                                                 const float* __restrict__ bias,
                                                 OutT* __restrict__ C,
                                                 unsigned short* __restrict__ Vt,
                                                 int M, int N, int K)
{
    __shared__ __align__(16) unsigned short As[64 * 256];   // 32 KB
    __shared__ __align__(16) unsigned short Bs[64 * 256];   // 32 KB
    const int tid  = threadIdx.x;
    const int w    = tid >> 6;
    const int lane = tid & 63;
    const int quad = lane >> 4;
    const int l16  = lane & 15;
    const int m0 = blockIdx.y * 64;
    const int n0 = blockIdx.x * 64;

    // staging geometry: GLD g covers rows {2g, 2g+1} (512 B each); lane l ->
    // row 2g+(l>>5), slot l&31, source chunk (l&31)^(row&7).
    const int rowin = lane >> 5;     // 0..1
    const int slot  = lane & 31;

    int aoff[8], boff[8];
    #pragma unroll
    for (int j = 0; j < 8; ++j) {
        const int g   = w * 8 + j;
        const int row = 2 * g + rowin;
        const int ch  = slot ^ (row & 7);
        aoff[j] = (m0 + row) * K + ch * 8;
        boff[j] = (n0 + row) * K + ch * 8;
    }

    floatx4 acc[4] = {};
    const int niter = K >> 8;
    for (int it = 0; it < niter; ++it) {
        const int k0 = it << 8;
        __syncthreads();                      // prev iteration's LDS reads done
        #pragma unroll
        for (int j = 0; j < 8; ++j) {
            const int g = w * 8 + j;
            GLD(A  + aoff[j] + k0, As + g * 512);
            GLD(Bw + boff[j] + k0, Bs + g * 512);
        }
        __syncthreads();                      // vmcnt(0) drain: tile resident

        #pragma unroll
        for (int kc = 0; kc < 8; ++kc) {
            const int s = (kc * 4 + quad) ^ (l16 & 7);
            short8 af = *(const short8*)&As[(w * 16 + l16) * 256 + s * 8];
            #pragma unroll
            for (int nt = 0; nt < 4; ++nt) {
                short8 bf = *(const short8*)&Bs[(nt * 16 + l16) * 256 + s * 8];
                acc[nt] = __builtin_amdgcn_mfma_f32_16x16x32_bf16(af, bf, acc[nt], 0, 0, 0);
            }
        }
    }

    // C/D layout: col = lane&15, row = quad*4 + reg
    #pragma unroll
    for (int nt = 0; nt < 4; ++nt) {
        const int col = n0 + nt * 16 + l16;
        const float bz = bias[col];
        if (VT_SPLIT && col >= 2 * HH) {     // V third -> transposed bf16 Vt[d][t]
            const int d = col - 2 * HH;
            const int t = m0 + w * 16 + quad * 4;
            ushort4 pk;
            pk.x = f2bf(acc[nt][0] + bz);
            pk.y = f2bf(acc[nt][1] + bz);
            pk.z = f2bf(acc[nt][2] + bz);
            pk.w = f2bf(acc[nt][3] + bz);
            *(ushort4*)&Vt[(size_t)d * VTS + t] = pk;
        } else {
            #pragma unroll
            for (int r = 0; r < 4; ++r) {
                const int row = m0 + w * 16 + quad * 4 + r;
                store_c(C, (size_t)row * N + col, acc[nt][r] + bz);
            }
        }
    }
}

// Fused attention: one block (256 thr) per (head, 64-query tile).
// Q,K staged swizzled via global_load_lds; QK^T MFMA; softmax in registers
// (row spread over 16 lanes x 12 frags -> xor-shuffle over lane bits 0..3);
// P -> padded LDS; PV MFMA against pre-transposed Vt; bf16 O out.
__global__ __launch_bounds__(256) void attn_fused(const unsigned short* __restrict__ qkv,
                                                  const unsigned short* __restrict__ VtG,
                                                  unsigned short* __restrict__ Oout)
{
    __shared__ __align__(16) unsigned short Qs[64 * 64];     //  8 KB swizzled
    __shared__ __align__(16) unsigned short Ks[192 * 64];    // 24 KB swizzled
    __shared__ __align__(16) unsigned short Vts[64 * VTS];   // 25.6 KB flat copy
    __shared__ __align__(16) unsigned short Ps[64 * VTS];    // 25.6 KB padded

    const int h  = blockIdx.x;
    const int q0 = blockIdx.y * 64;
    const int tid  = threadIdx.x;
    const int w    = tid >> 6;
    const int lane = tid & 63;
    const int quad = lane >> 4;
    const int l16  = lane & 15;

    const int rin = lane >> 3;      // 0..7  row within an 8-row GLD
    const int ch8 = (lane & 7) ^ rin;   // swizzled source chunk

    // ---- stage Q (8 GLDs), K (24 GLDs), Vt (25 flat GLDs) ----
    #pragma unroll
    for (int j = 0; j < 2; ++j) {
        const int g = w * 2 + j;
        GLD(qkv + (size_t)(q0 + g * 8 + rin) * H3 + h * HD + ch8 * 8, Qs + g * 512);
    }
    #pragma unroll
    for (int j = 0; j < 6; ++j) {
        const int g = w * 6 + j;
        GLD(qkv + (size_t)(g * 8 + rin) * H3 + HH + h * HD + ch8 * 8, Ks + g * 512);
    }
    #pragma unroll
    for (int j = 0; j < 7; ++j) {
        const int g = w * 7 + j;                       // 0..27
        if (g < 25)                                    // 64*VTS*2 B = 25 KiB
            GLD(VtG + (size_t)h * HD * VTS + g * 512 + lane * 8, Vts + g * 512);
    }
    __syncthreads();

    // ---- S = Q K^T (wave w owns q rows w*16..w*16+15) ----
    floatx4 accs[12] = {};
    #pragma unroll
    for (int kc = 0; kc < 2; ++kc) {
        const int s = (kc * 4 + quad) ^ (l16 & 7);
        short8 af = *(const short8*)&Qs[(w * 16 + l16) * 64 + s * 8];
        #pragma unroll
        for (int nt = 0; nt < 12; ++nt) {
            short8 bf = *(const short8*)&Ks[(nt * 16 + l16) * 64 + s * 8];
            accs[nt] = __builtin_amdgcn_mfma_f32_16x16x32_bf16(af, bf, accs[nt], 0, 0, 0);
        }
    }

    // ---- softmax over 192 keys (12 frags x 16 lanes), scale 1/8 ----
    float invr[4];
    #pragma unroll
    for (int r = 0; r < 4; ++r) {
        float m = accs[0][r];
        #pragma unroll
        for (int nt = 1; nt < 12; ++nt) m = fmaxf(m, accs[nt][r]);
        #pragma unroll
        for (int off = 1; off < 16; off <<= 1) m = fmaxf(m, __shfl_xor(m, off));
        float sum = 0.f;
        #pragma unroll
        for (int nt = 0; nt < 12; ++nt) {
            const float p = __expf((accs[nt][r] - m) * 0.125f);
            accs[nt][r] = p;
            sum += p;
        }
        #pragma unroll
        for (int off = 1; off < 16; off <<= 1) sum += __shfl_xor(sum, off);
        invr[r] = 1.f / sum;
        const int row = w * 16 + quad * 4 + r;
        #pragma unroll
        for (int nt = 0; nt < 12; ++nt)
            Ps[row * VTS + nt * 16 + l16] = f2bf(accs[nt][r]);
    }
    __syncthreads();

    // ---- O = P V  (contract over keys; Vt rows are d, cols are keys) ----
    floatx4 acco[4] = {};
    #pragma unroll
    for (int kc = 0; kc < 6; ++kc) {
        short8 af = *(const short8*)&Ps[(w * 16 + l16) * VTS + kc * 32 + quad * 8];
        #pragma unroll
        for (int nt = 0; nt < 4; ++nt) {
            short8 bf = *(const short8*)&Vts[(nt * 16 + l16) * VTS + kc * 32 + quad * 8];
            acco[nt] = __builtin_amdgcn_mfma_f32_16x16x32_bf16(af, bf, acco[nt], 0, 0, 0);
        }
    }

    #pragma unroll
    for (int nt = 0; nt < 4; ++nt) {
        const int d = h * HD + nt * 16 + l16;
        #pragma unroll
        for (int r = 0; r < 4; ++r) {
            const int q = q0 + w * 16 + quad * 4 + r;
            Oout[(size_t)q * HH + d] = f2bf(acco[nt][r] * invr[r]);
        }
    }
}

// xout = xin + LN(y)*g + b ; dual write fp32 + bf16  (one block per row)
__global__ __launch_bounds__(256) void ln_residual(const float* __restrict__ y,
                                                   const float* __restrict__ xin,
                                                   const float* __restrict__ g,
                                                   const float* __restrict__ b,
                                                   float* __restrict__ xout,
                                                   unsigned short* __restrict__ xout_bf)
{
    const int row = blockIdx.x;
    const int tid = threadIdx.x;

    const float4 v = *(const float4*)&y[row * HH + tid * 4];
    float s  = v.x + v.y + v.z + v.w;
    float sq = v.x * v.x + v.y * v.y + v.z * v.z + v.w * v.w;

    #pragma unroll
    for (int off = 32; off > 0; off >>= 1) {
        s  += __shfl_down(s,  off);
        sq += __shfl_down(sq, off);
    }
    __shared__ float ws[4], wq[4];
    const int wave = tid >> 6;
    if ((tid & 63) == 0) { ws[wave] = s; wq[wave] = sq; }
    __syncthreads();
    float ts = 0.f, tq = 0.f;
    #pragma unroll
    for (int w = 0; w < 4; ++w) { ts += ws[w]; tq += wq[w]; }

    const float mean = ts * (1.f / HH);
    const float var  = tq * (1.f / HH) - mean * mean;
    const float r    = rsqrtf(var + LN_EPS);

    const float4 xi = *(const float4*)&xin[row * HH + tid * 4];
    const float4 gg = *(const float4*)&g[tid * 4];
    const float4 bb = *(const float4*)&b[tid * 4];
    float4 o;
    o.x = xi.x + (v.x - mean) * r * gg.x + bb.x;
    o.y = xi.y + (v.y - mean) * r * gg.y + bb.y;
    o.z = xi.z + (v.z - mean) * r * gg.z + bb.z;
    o.w = xi.w + (v.w - mean) * r * gg.w + bb.w;
    *(float4*)&xout[row * HH + tid * 4] = o;
    ushort4 ob;
    ob.x = f2bf(o.x); ob.y = f2bf(o.y); ob.z = f2bf(o.z); ob.w = f2bf(o.w);
    *(ushort4*)&xout_bf[row * HH + tid * 4] = ob;
}

extern "C" void kernel_launch(void* const* d_in, const int* in_sizes, int n_in,
                              void* d_out, int out_size, void* d_ws, size_t ws_size,
                              hipStream_t stream)
{
    const float* nodes     = (const float*)d_in[0];
    const float* mha_in_w  = (const float*)d_in[14];   // [2, 3H, H]
    const float* mha_in_b  = (const float*)d_in[15];   // [2, 3H]
    const float* mha_out_w = (const float*)d_in[16];   // [2, H, H]
    const float* mha_out_b = (const float*)d_in[17];   // [2, H]
    const float* mha_ln_g  = (const float*)d_in[18];   // [2, H]
    const float* mha_ln_b  = (const float*)d_in[19];   // [2, H]
    float* out = (float*)d_out;

    // ---- ws carve (bf16 region then fp32 region; all 16-B aligned) ----
    unsigned short* u = (unsigned short*)d_ws;
    unsigned short* bf_inW   = u;  u += 2 * H3 * HH;    // 6291456
    unsigned short* bf_outW  = u;  u += 2 * HH * HH;    // 2097152
    unsigned short* bf_nodes = u;  u += TT * HH;        // 196608
    unsigned short* bf_x1    = u;  u += TT * HH;
    unsigned short* bf_qkv   = u;  u += TT * H3;        // (V third unused)
    unsigned short* bf_o     = u;  u += TT * HH;
    unsigned short* Vt       = u;  u += HH * VTS;       // [1024][200] bf16
    float* f = (float*)u;
    float* proj = f;  f += TT * HH;
    float* x1   = f;  f += TT * HH;

    // ---- one-time fp32 -> bf16 (in_w | out_w | nodes) in one dispatch ----
    {
        const int na4 = (2 * H3 * HH) / 4;
        const int nb4 = (2 * HH * HH) / 4;
        const int nc4 = (TT * HH) / 4;
        const int tot = na4 + nb4 + nc4;
        cvt3<<<(tot + 255) / 256, 256, 0, stream>>>(
            mha_in_w, na4, mha_out_w, nb4, nodes, nc4, bf_inW, bf_outW, bf_nodes);
    }

    const float* x_f = nodes;
    const unsigned short* x_bf = bf_nodes;
    for (int l = 0; l < 2; ++l) {
        float* xout = (l == 0) ? x1 : out;

        gemm_bf16<unsigned short, 1><<<dim3(H3 / 64, TT / 64), 256, 0, stream>>>(
            x_bf, bf_inW + (size_t)l * H3 * HH, mha_in_b + l * H3, bf_qkv, Vt, TT, H3, HH);

        attn_fused<<<dim3(NHH, TT / 64), 256, 0, stream>>>(bf_qkv, Vt, bf_o);

        gemm_bf16<float, 0><<<dim3(HH / 64, TT / 64), 256, 0, stream>>>(
            bf_o, bf_outW + (size_t)l * HH * HH, mha_out_b + l * HH, proj, nullptr, TT, HH, HH);

        ln_residual<<<TT, 256, 0, stream>>>(
            proj, x_f, mha_ln_g + l * HH, mha_ln_b + l * HH, xout, bf_x1);

        x_f = xout;
        x_bf = bf_x1;
    }
}